// Round 8
// baseline (371.389 us; speedup 1.0000x reference)
//
#include <hip/hip_runtime.h>

// GNN: N=50000 nodes, E=800000 edges, IN=128, HID=64, OUT=128, EH=32, 3 etypes, 2 ntypes.
//
// Strategy:
//   feat @ eW[e] = nf[src] @ eW[e][:IN] + nf[dst] @ eW[e][IN:]
//   => per-node projections P[n][192], per-edge work = adds + relu + reg accumulation
//      (gather over CSR-by-dst). Node MLP type-partitioned. proj via MFMA bf16 3-term split.
//
// R1: multi-block scan. R2: mlp type-partitioned. R3: CSR replicated-rank + atomic-free
//     scatter. R4/R5: conflict-free quad layouts. R6: LDS-BW floor identified.
// R7: proj -> MFMA 16x16x32 bf16 hi/lo split (83 -> ~12 us). Layouts verified.
// R8: aggregate was 51.5 us x2 (VALU 44%: ~2/3 of per-edge instrs were type
//     bookkeeping: et unpack, pdb cndmask, 6-instr type counting + masked acc).
//     CSR rows now SORTED BY TYPE (rank/fill keyed (dst,et,replica), 24 ctrs/node);
//     per-type counts free from scan (cnts2); edata stores precomputed byte offset
//     src*768+et*128 (no per-edge mul). Inner loop: load pk -> load P -> fmax/add.

typedef __attribute__((ext_vector_type(8))) short bf16x8_t;   // 8 bf16 in 4 VGPRs
typedef __attribute__((ext_vector_type(4))) float f32x4_t;

__device__ __forceinline__ void cvt_split(float x, unsigned short& h, unsigned short& l) {
  unsigned u = __float_as_uint(x);
  unsigned rh = u + 0x7FFFu + ((u >> 16) & 1u);
  h = (unsigned short)(rh >> 16);
  float xh = __uint_as_float((unsigned)h << 16);
  float xl = x - xh;
  unsigned v = __float_as_uint(xl);
  unsigned rl = v + 0x7FFFu + ((v >> 16) & 1u);
  l = (unsigned short)(rl >> 16);
}

// ---------------- CSR build (type-sorted rows) ----------------

__global__ __launch_bounds__(256) void rank_kernel(const int* __restrict__ dst,
                                                   const int* __restrict__ etype,
                                                   int* __restrict__ deg24,
                                                   int* __restrict__ rank, int E) {
  int i = blockIdx.x * 256 + threadIdx.x;
  if (i < E) {
    int d = dst[i];
    int et = etype[i];
    int r = (i >> 8) & 7;
    rank[i] = atomicAdd(&deg24[(size_t)d * 24 + et * 8 + r], 1);
  }
}

// fold 24 counters/node -> exclusive offsets in place; emit per-node degree for
// block scan; also emit cnts2[v] = {c0, c0+c1} for aggregate's segment bounds.
__global__ __launch_bounds__(256) void scan1_kernel(int* __restrict__ deg24,
                                                    int* __restrict__ rowstart,
                                                    int* __restrict__ bsum,
                                                    int* __restrict__ cnts2, int n) {
  __shared__ int tmp[256];
  int t = threadIdx.x;
  int base = blockIdx.x * 1024 + t * 4;
  int vdeg[4];
#pragma unroll
  for (int q = 0; q < 4; ++q) {
    int v = base + q;
    int d = 0;
    if (v < n) {
      int* p = deg24 + (size_t)v * 24;
      int run = 0, c0 = 0, c01 = 0;
#pragma unroll
      for (int jb = 0; jb < 6; ++jb) {
        if (jb == 2) c0 = run;
        if (jb == 4) c01 = run;
        int4 a = *(int4*)(p + jb * 4);
        int t0 = a.x, t1 = a.y, t2 = a.z, t3 = a.w;
        a.x = run; run += t0;
        a.y = run; run += t1;
        a.z = run; run += t2;
        a.w = run; run += t3;
        *(int4*)(p + jb * 4) = a;
      }
      d = run;
      cnts2[2 * v] = c0;
      cnts2[2 * v + 1] = c01;
    }
    vdeg[q] = d;
  }
  int s = vdeg[0] + vdeg[1] + vdeg[2] + vdeg[3];
  tmp[t] = s;
  __syncthreads();
  for (int off = 1; off < 256; off <<= 1) {
    int u = (t >= off) ? tmp[t - off] : 0;
    __syncthreads();
    tmp[t] += u;
    __syncthreads();
  }
  int excl = tmp[t] - s;
  if (base < n)     rowstart[base]     = excl;
  if (base + 1 < n) rowstart[base + 1] = excl + vdeg[0];
  if (base + 2 < n) rowstart[base + 2] = excl + vdeg[0] + vdeg[1];
  if (base + 3 < n) rowstart[base + 3] = excl + vdeg[0] + vdeg[1] + vdeg[2];
  if (t == 255) bsum[blockIdx.x] = tmp[255];
}

__global__ __launch_bounds__(64) void scan2_kernel(const int* __restrict__ bsum,
                                                   int* __restrict__ boff, int nb,
                                                   int* __restrict__ rowstart, int n) {
  int lane = threadIdx.x;
  int v = (lane < nb) ? bsum[lane] : 0;
  int incl = v;
  for (int off = 1; off < 64; off <<= 1) {
    int u = __shfl_up(incl, off, 64);
    if (lane >= off) incl += u;
  }
  if (lane < nb) boff[lane] = incl - v;
  if (lane == 63) rowstart[n] = incl;
}

__global__ __launch_bounds__(256) void scan3_kernel(int* __restrict__ rowstart,
                                                    const int* __restrict__ boff, int n) {
  int i = blockIdx.x * 256 + threadIdx.x;
  if (i < n) rowstart[i] += boff[i >> 10];
}

// atomic-free scatter; edata = byte offset into P: src*768 + et*128
__global__ __launch_bounds__(256) void fill_kernel(const int* __restrict__ src,
                                                   const int* __restrict__ dst,
                                                   const int* __restrict__ etype,
                                                   const int* __restrict__ rank,
                                                   const int* __restrict__ rowstart,
                                                   const int* __restrict__ deg24,
                                                   int* __restrict__ edata, int E) {
  int i = blockIdx.x * 256 + threadIdx.x;
  if (i < E) {
    int d = dst[i];
    int et = etype[i];
    int r = (i >> 8) & 7;
    int pos = rowstart[d] + deg24[(size_t)d * 24 + et * 8 + r] + rank[i];
    edata[pos] = src[i] * 768 + et * 128;
  }
}

// ---------------- node partition by type ----------------

__global__ __launch_bounds__(256) void partition_kernel(const int* __restrict__ ntype,
                                                        int* __restrict__ idxbuf,
                                                        int* __restrict__ tcnt,
                                                        int n, int ncap) {
  int i = blockIdx.x * 256 + threadIdx.x;
  int lane = threadIdx.x & 63;
  int t = (i < n) ? ntype[i] : -1;
  unsigned long long m0 = __ballot(t == 0);
  unsigned long long m1 = __ballot(t == 1);
  int b0 = 0, b1 = 0;
  if (lane == 0) {
    b0 = atomicAdd(&tcnt[0], (int)__popcll(m0));
    b1 = atomicAdd(&tcnt[1], (int)__popcll(m1));
  }
  b0 = __shfl(b0, 0);
  b1 = __shfl(b1, 0);
  unsigned long long below = (1ull << lane) - 1ull;
  if (t == 0) idxbuf[b0 + (int)__popcll(m0 & below)] = i;
  else if (t == 1) idxbuf[ncap + b1 + (int)__popcll(m1 & below)] = i;
}

// ---------------- W fragment prep (once): hi/lo bf16 frags, frag-major ----------------

template <int IN>
__global__ __launch_bounds__(256) void prep_w(const float* __restrict__ eW,
                                              float* __restrict__ wfh,
                                              float* __restrict__ wfl) {
  constexpr int KC = IN / 32;
  int id = blockIdx.x * 256 + threadIdx.x;
  if (id >= 12 * KC * 64) return;
  int lane = id & 63;
  int fk = id >> 6;
  int kc = fk % KC, ct = fk / KC;
  int n = ct * 16 + (lane & 15);
  int kb = kc * 32 + ((lane >> 4) & 3) * 8;
  int half = (n >= 96) ? 1 : 0;
  int jj = n - 96 * half;
  int e = jj >> 5, o = jj & 31;
  const float* wp = eW + ((size_t)((e * 2 + half) * IN) + kb) * 32 + o;
  bf16x8_t hv, lv;
#pragma unroll
  for (int j = 0; j < 8; ++j) {
    unsigned short h, l;
    cvt_split(wp[(size_t)j * 32], h, l);
    hv[j] = (short)h;
    lv[j] = (short)l;
  }
  *(bf16x8_t*)(wfh + (size_t)id * 4) = hv;
  *(bf16x8_t*)(wfl + (size_t)id * 4) = lv;
}

// ---------------- node projection GEMM via MFMA ----------------

template <int IN>
__global__ __launch_bounds__(256) void proj_mfma(const float* __restrict__ X,
                                                 const float* __restrict__ wfh,
                                                 const float* __restrict__ wfl,
                                                 float* __restrict__ P, int n) {
  constexpr int KC = IN / 32;
  __shared__ short Ah[4 * KC * 64 * 8];
  __shared__ short Al[4 * KC * 64 * 8];
  const int tx = threadIdx.x;
  const int base = blockIdx.x * 64;

  for (int q = tx; q < 4 * KC * 64; q += 256) {
    int lane = q & 63;
    int fk = q >> 6;
    int kc = fk % KC, nt = fk / KC;
    int node = base + nt * 16 + (lane & 15);
    int kb = kc * 32 + ((lane >> 4) & 3) * 8;
    float xs[8];
    if (node < n) {
      float4 a = *(const float4*)(X + (size_t)node * IN + kb);
      float4 b = *(const float4*)(X + (size_t)node * IN + kb + 4);
      xs[0] = a.x; xs[1] = a.y; xs[2] = a.z; xs[3] = a.w;
      xs[4] = b.x; xs[5] = b.y; xs[6] = b.z; xs[7] = b.w;
    } else {
#pragma unroll
      for (int j = 0; j < 8; ++j) xs[j] = 0.f;
    }
    bf16x8_t hv, lv;
#pragma unroll
    for (int j = 0; j < 8; ++j) {
      unsigned short h, l;
      cvt_split(xs[j], h, l);
      hv[j] = (short)h;
      lv[j] = (short)l;
    }
    *(bf16x8_t*)(Ah + (size_t)q * 8) = hv;
    *(bf16x8_t*)(Al + (size_t)q * 8) = lv;
  }
  __syncthreads();

  const int wave = tx >> 6;
  const int lane = tx & 63;

  f32x4_t acc[4][3];
#pragma unroll
  for (int nt = 0; nt < 4; ++nt)
#pragma unroll
    for (int c = 0; c < 3; ++c) acc[nt][c] = (f32x4_t){0.f, 0.f, 0.f, 0.f};

  for (int kc = 0; kc < KC; ++kc) {
    bf16x8_t Bh[3], Bl[3];
#pragma unroll
    for (int c = 0; c < 3; ++c) {
      int ct = wave * 3 + c;
      size_t idx = ((size_t)(ct * KC + kc) * 64 + lane) * 4;
      Bh[c] = *(const bf16x8_t*)(wfh + idx);
      Bl[c] = *(const bf16x8_t*)(wfl + idx);
    }
#pragma unroll
    for (int nt = 0; nt < 4; ++nt) {
      size_t idx = ((size_t)(nt * KC + kc) * 64 + lane) * 8;
      bf16x8_t ah = *(const bf16x8_t*)(Ah + idx);
      bf16x8_t al = *(const bf16x8_t*)(Al + idx);
#pragma unroll
      for (int c = 0; c < 3; ++c) {
        acc[nt][c] = __builtin_amdgcn_mfma_f32_16x16x32_bf16(ah, Bh[c], acc[nt][c], 0, 0, 0);
        acc[nt][c] = __builtin_amdgcn_mfma_f32_16x16x32_bf16(ah, Bl[c], acc[nt][c], 0, 0, 0);
        acc[nt][c] = __builtin_amdgcn_mfma_f32_16x16x32_bf16(al, Bh[c], acc[nt][c], 0, 0, 0);
      }
    }
  }

  const int row0 = ((lane >> 4) & 3) * 4;
  const int col = lane & 15;
#pragma unroll
  for (int nt = 0; nt < 4; ++nt) {
#pragma unroll
    for (int c = 0; c < 3; ++c) {
      int jcol = (wave * 3 + c) * 16 + col;
#pragma unroll
      for (int r = 0; r < 4; ++r) {
        int node = base + nt * 16 + row0 + r;
        if (node < n) P[(size_t)node * 192 + jcol] = acc[nt][c][r];
      }
    }
  }
}

// ---------------- edge aggregation (type-sorted CSR) ----------------
// Wave per node; rows sorted by type -> 3 segment loops, no per-edge type logic.
// edata[i] = byte offset (src*768 + et*128); counts from cnts2.

__global__ __launch_bounds__(256) void aggregate_kernel(const float* __restrict__ P,
                                                        const int* __restrict__ rowstart,
                                                        const int* __restrict__ cnts2,
                                                        const int* __restrict__ edata,
                                                        const float* __restrict__ eb,
                                                        float* __restrict__ h, int n) {
  int wid = (blockIdx.x * 256 + threadIdx.x) >> 6;
  if (wid >= n) return;
  int lane = threadIdx.x & 63;
  int o = lane & 31, slot = lane >> 5;
  const float* Pd = P + (size_t)wid * 192 + 96;
  float pdb0 = Pd[o] + eb[o];
  float pdb1 = Pd[32 + o] + eb[32 + o];
  float pdb2 = Pd[64 + o] + eb[64 + o];
  int s = rowstart[wid], e = rowstart[wid + 1];
  int c0 = cnts2[2 * wid], c01 = cnts2[2 * wid + 1];
  int b1 = s + c0, b2 = s + c01;
  const char* Pb = (const char*)P;
  int o4 = o * 4;
  float a0 = 0.f, a1 = 0.f, a2 = 0.f;
  for (int i = s + slot; i < b1; i += 2)
    a0 += fmaxf(*(const float*)(Pb + edata[i] + o4) + pdb0, 0.f);
  for (int i = b1 + slot; i < b2; i += 2)
    a1 += fmaxf(*(const float*)(Pb + edata[i] + o4) + pdb1, 0.f);
  for (int i = b2 + slot; i < e; i += 2)
    a2 += fmaxf(*(const float*)(Pb + edata[i] + o4) + pdb2, 0.f);
  a0 += __shfl_xor(a0, 32);
  a1 += __shfl_xor(a1, 32);
  a2 += __shfl_xor(a2, 32);
  if (slot == 0) {
    float* hn = h + (size_t)wid * 96;
    hn[o] = a0 / fmaxf((float)c0, 1.f);
    hn[32 + o] = a1 / fmaxf((float)(c01 - c0), 1.f);
    hn[64 + o] = a2 / fmaxf((float)(e - s - c01), 1.f);
  }
}

// ---------------- node MLP (type-partitioned), quad-transposed Ws ----------------

template <int OUT>
__global__ __launch_bounds__(256) void mlp2_kernel(const float* __restrict__ H,
                                                   const float* __restrict__ nW,
                                                   const float* __restrict__ nb,
                                                   const int* __restrict__ idxbuf,
                                                   const int* __restrict__ tcnt,
                                                   float* __restrict__ out, int ncap) {
  constexpr int CO = OUT / 32;
  __shared__ float Xs[64 * 32];
  __shared__ float Ws[8 * OUT * 4];

  int c0 = tcnt[0];
  int nb0 = (c0 + 63) >> 6;
  int t, base, cnt;
  if ((int)blockIdx.x < nb0) {
    t = 0; base = blockIdx.x << 6; cnt = c0;
  } else {
    t = 1; base = ((int)blockIdx.x - nb0) << 6; cnt = tcnt[1];
    if (base >= cnt) return;
  }
  const float* W = nW + (size_t)t * 96 * OUT;
  const float* bias = nb + t * OUT;
  const int* il = idxbuf + (size_t)t * ncap;

  const int tx = threadIdx.x;
  const int t32 = tx & 31;
  const int ng = tx >> 5;

  float acc[8][CO];
#pragma unroll
  for (int i = 0; i < 8; ++i)
#pragma unroll
    for (int c = 0; c < CO; ++c) acc[i][c] = 0.f;

  for (int k0 = 0; k0 < 96; k0 += 32) {
    for (int id = tx; id < 512; id += 256) {
      int i = id >> 3, kk4 = (id & 7) * 4;
      float4 v = make_float4(0.f, 0.f, 0.f, 0.f);
      if (base + i < cnt) {
        int row = il[base + i];
        v = *(const float4*)(H + (size_t)row * 96 + k0 + kk4);
      }
      *(float4*)(Xs + i * 32 + kk4) = v;
    }
    for (int id = tx; id < 8 * OUT; id += 256) {
      int g = id / OUT;
      int j = id % OUT;
      const float* wp = W + (size_t)(k0 + 4 * g) * OUT + j;
      float4 v = make_float4(wp[0], wp[OUT], wp[2 * OUT], wp[3 * OUT]);
      *(float4*)(Ws + (size_t)id * 4) = v;
    }
    __syncthreads();
#pragma unroll
    for (int g = 0; g < 8; ++g) {
      float4 xv[8], wv[CO];
#pragma unroll
      for (int i = 0; i < 8; ++i) xv[i] = *(const float4*)(Xs + (ng * 8 + i) * 32 + 4 * g);
#pragma unroll
      for (int c = 0; c < CO; ++c) wv[c] = *(const float4*)(Ws + ((size_t)g * OUT + t32 + 32 * c) * 4);
#pragma unroll
      for (int i = 0; i < 8; ++i)
#pragma unroll
        for (int c = 0; c < CO; ++c) {
          acc[i][c] = fmaf(xv[i].x, wv[c].x, acc[i][c]);
          acc[i][c] = fmaf(xv[i].y, wv[c].y, acc[i][c]);
          acc[i][c] = fmaf(xv[i].z, wv[c].z, acc[i][c]);
          acc[i][c] = fmaf(xv[i].w, wv[c].w, acc[i][c]);
        }
    }
    __syncthreads();
  }

  float bj[CO];
#pragma unroll
  for (int c = 0; c < CO; ++c) bj[c] = bias[t32 + 32 * c];
#pragma unroll
  for (int i = 0; i < 8; ++i) {
    int slot = base + ng * 8 + i;
    if (slot < cnt) {
      int row = il[slot];
#pragma unroll
      for (int c = 0; c < CO; ++c)
        out[(size_t)row * OUT + t32 + 32 * c] = fmaxf(acc[i][c] + bj[c], 0.f);
    }
  }
}

// ---------------- launch ----------------

extern "C" void kernel_launch(void* const* d_in, const int* in_sizes, int n_in,
                              void* d_out, int out_size, void* d_ws, size_t ws_size,
                              hipStream_t stream) {
  const float* nf    = (const float*)d_in[0];
  const int*   eidx  = (const int*)d_in[1];
  const int*   etype = (const int*)d_in[2];
  const int*   ntype = (const int*)d_in[3];
  const float* eW0   = (const float*)d_in[4];
  const float* eb0   = (const float*)d_in[5];
  const float* nW0   = (const float*)d_in[6];
  const float* nb0   = (const float*)d_in[7];
  const float* eW1   = (const float*)d_in[8];
  const float* eb1   = (const float*)d_in[9];
  const float* nW1   = (const float*)d_in[10];
  const float* nb1   = (const float*)d_in[11];
  const int N = in_sizes[3];
  const int E = in_sizes[2];
  const int* srcv = eidx;
  const int* dstv = eidx + E;

  // workspace layout; rank aliases h96, deg24 aliases h64 (both only used during
  // CSR build, which completes before aggregate/mlp write those buffers).
  // cnts2 is dedicated (aggregate reads it in BOTH layers, after h64 is overwritten).
  float* P   = (float*)d_ws;                     // N*192
  float* h96 = P + (size_t)N * 192;              // N*96
  float* h64 = h96 + (size_t)N * 96;             // N*64
  int* rowstart = (int*)(h64 + (size_t)N * 64);  // N+1 (padded)
  int* tcnt     = rowstart + ((N + 4) & ~3);     // 2
  int* bsum     = tcnt + 2;                      // 64
  int* boff     = bsum + 64;                     // 64
  int* cnts2    = boff + 64;                     // 2*N
  int* idxbuf   = cnts2 + 2 * N;                 // 2*N
  int* edata    = idxbuf + 2 * N;                // E
  float* wf0h   = (float*)(edata + E);           // 12288
  float* wf0l   = wf0h + 12288;                  // 12288
  float* wf1h   = wf0l + 12288;                  // 6144
  float* wf1l   = wf1h + 6144;                   // 6144
  int* rank     = (int*)h96;                     // E   (alias)
  int* deg24    = (int*)h64;                     // 24N (alias; 24N ints <= N*64 floats)

  const int nsb = (N + 1023) / 1024;
  const int egrid = (E + 255) / 256;

  hipMemsetAsync(deg24, 0, (size_t)N * 24 * sizeof(int), stream);
  hipMemsetAsync(tcnt, 0, 2 * sizeof(int), stream);
  prep_w<128><<<12, 256, 0, stream>>>(eW0, wf0h, wf0l);
  prep_w<64><<<6, 256, 0, stream>>>(eW1, wf1h, wf1l);
  rank_kernel<<<egrid, 256, 0, stream>>>(dstv, etype, deg24, rank, E);
  scan1_kernel<<<nsb, 256, 0, stream>>>(deg24, rowstart, bsum, cnts2, N);
  scan2_kernel<<<1, 64, 0, stream>>>(bsum, boff, nsb, rowstart, N);
  scan3_kernel<<<(N + 255) / 256, 256, 0, stream>>>(rowstart, boff, N);
  fill_kernel<<<egrid, 256, 0, stream>>>(srcv, dstv, etype, rank, rowstart, deg24, edata, E);
  partition_kernel<<<(N + 255) / 256, 256, 0, stream>>>(ntype, idxbuf, tcnt, N, N);

  const int pgrid = (N + 63) / 64;
  int agrid = (N + 3) / 4;
  int mgrid = (N + 63) / 64 + 2;

  // layer 0: 128 -> 64
  proj_mfma<128><<<pgrid, 256, 0, stream>>>(nf, wf0h, wf0l, P, N);
  aggregate_kernel<<<agrid, 256, 0, stream>>>(P, rowstart, cnts2, edata, eb0, h96, N);
  mlp2_kernel<64><<<mgrid, 256, 0, stream>>>(h96, nW0, nb0, idxbuf, tcnt, h64, N);

  // layer 1: 64 -> 128
  proj_mfma<64><<<pgrid, 256, 0, stream>>>(h64, wf1h, wf1l, P, N);
  aggregate_kernel<<<agrid, 256, 0, stream>>>(P, rowstart, cnts2, edata, eb1, h96, N);
  mlp2_kernel<128><<<mgrid, 256, 0, stream>>>(h96, nW1, nb1, idxbuf, tcnt, (float*)d_out, N);
}

// Round 9
// 319.899 us; speedup vs baseline: 1.1610x; 1.1610x over previous
//
#include <hip/hip_runtime.h>

// GNN: N=50000 nodes, E=800000 edges, IN=128, HID=64, OUT=128, EH=32, 3 etypes, 2 ntypes.
//
// Strategy:
//   feat @ eW[e] = nf[src] @ eW[e][:IN] + nf[dst] @ eW[e][IN:]
//   => per-node projections P[n][192], per-edge work = adds + relu + reg accumulation
//      (gather over CSR-by-dst). Node MLP type-partitioned. proj via MFMA bf16 3-term split.
//
// R1: multi-block scan. R2: mlp type-partitioned. R3: CSR replicated-rank + atomic-free
//     scatter. R4/R5: conflict-free quad layouts. R6: LDS-BW floor. R7: proj MFMA.
// R8 post-mortem: aggregate is LATENCY-bound (VALU 44->24% with duration flat 52us;
//     Little's law: ~1.5 outstanding 128B loads/wave @ ~900cyc ~= measured 2 TB/s).
// R9: revert CSR to cheap deg8 build (type-sort bought nothing); pack et into low
//     bits of byte offset (edata = src*768 + et*128 + et; base 128B-aligned).
//     aggregate: manual unroll-4 per slot -> 8 independent P loads in flight/wave.

typedef __attribute__((ext_vector_type(8))) short bf16x8_t;   // 8 bf16 in 4 VGPRs
typedef __attribute__((ext_vector_type(4))) float f32x4_t;

__device__ __forceinline__ void cvt_split(float x, unsigned short& h, unsigned short& l) {
  unsigned u = __float_as_uint(x);
  unsigned rh = u + 0x7FFFu + ((u >> 16) & 1u);
  h = (unsigned short)(rh >> 16);
  float xh = __uint_as_float((unsigned)h << 16);
  float xl = x - xh;
  unsigned v = __float_as_uint(xl);
  unsigned rl = v + 0x7FFFu + ((v >> 16) & 1u);
  l = (unsigned short)(rl >> 16);
}

// ---------------- CSR build (deg8 replicated-rank, atomic-free scatter) ----------------

__global__ __launch_bounds__(256) void rank_kernel(const int* __restrict__ dst,
                                                   int* __restrict__ deg8,
                                                   int* __restrict__ rank, int E) {
  int i = blockIdx.x * 256 + threadIdx.x;
  if (i < E) {
    int d = dst[i];
    int r = (i >> 8) & 7;
    rank[i] = atomicAdd(&deg8[d * 8 + r], 1);
  }
}

__global__ __launch_bounds__(256) void scan1_kernel(int* __restrict__ deg8,
                                                    int* __restrict__ rowstart,
                                                    int* __restrict__ bsum, int n) {
  __shared__ int tmp[256];
  int t = threadIdx.x;
  int base = blockIdx.x * 1024 + t * 4;
  int vdeg[4];
#pragma unroll
  for (int q = 0; q < 4; ++q) {
    int v = base + q;
    int d = 0;
    if (v < n) {
      int4 a = *(int4*)(deg8 + (size_t)v * 8);
      int4 b = *(int4*)(deg8 + (size_t)v * 8 + 4);
      int p1 = a.x, p2 = p1 + a.y, p3 = p2 + a.z, p4 = p3 + a.w;
      int p5 = p4 + b.x, p6 = p5 + b.y, p7 = p6 + b.z;
      d = p7 + b.w;
      *(int4*)(deg8 + (size_t)v * 8) = make_int4(0, p1, p2, p3);
      *(int4*)(deg8 + (size_t)v * 8 + 4) = make_int4(p4, p5, p6, p7);
    }
    vdeg[q] = d;
  }
  int s = vdeg[0] + vdeg[1] + vdeg[2] + vdeg[3];
  tmp[t] = s;
  __syncthreads();
  for (int off = 1; off < 256; off <<= 1) {
    int u = (t >= off) ? tmp[t - off] : 0;
    __syncthreads();
    tmp[t] += u;
    __syncthreads();
  }
  int excl = tmp[t] - s;
  if (base < n)     rowstart[base]     = excl;
  if (base + 1 < n) rowstart[base + 1] = excl + vdeg[0];
  if (base + 2 < n) rowstart[base + 2] = excl + vdeg[0] + vdeg[1];
  if (base + 3 < n) rowstart[base + 3] = excl + vdeg[0] + vdeg[1] + vdeg[2];
  if (t == 255) bsum[blockIdx.x] = tmp[255];
}

__global__ __launch_bounds__(64) void scan2_kernel(const int* __restrict__ bsum,
                                                   int* __restrict__ boff, int nb,
                                                   int* __restrict__ rowstart, int n) {
  int lane = threadIdx.x;
  int v = (lane < nb) ? bsum[lane] : 0;
  int incl = v;
  for (int off = 1; off < 64; off <<= 1) {
    int u = __shfl_up(incl, off, 64);
    if (lane >= off) incl += u;
  }
  if (lane < nb) boff[lane] = incl - v;
  if (lane == 63) rowstart[n] = incl;
}

__global__ __launch_bounds__(256) void scan3_kernel(int* __restrict__ rowstart,
                                                    const int* __restrict__ boff, int n) {
  int i = blockIdx.x * 256 + threadIdx.x;
  if (i < n) rowstart[i] += boff[i >> 10];
}

// edata = byte offset src*768 + et*128, with et duplicated in the low 2 bits
// (base is 128B-aligned so low 7 bits are free).
__global__ __launch_bounds__(256) void fill_kernel(const int* __restrict__ src,
                                                   const int* __restrict__ dst,
                                                   const int* __restrict__ etype,
                                                   const int* __restrict__ rank,
                                                   const int* __restrict__ rowstart,
                                                   const int* __restrict__ deg8,
                                                   int* __restrict__ edata, int E) {
  int i = blockIdx.x * 256 + threadIdx.x;
  if (i < E) {
    int d = dst[i];
    int r = (i >> 8) & 7;
    int et = etype[i];
    int pos = rowstart[d] + deg8[d * 8 + r] + rank[i];
    edata[pos] = src[i] * 768 + et * 129;  // et*128 + et
  }
}

// ---------------- node partition by type ----------------

__global__ __launch_bounds__(256) void partition_kernel(const int* __restrict__ ntype,
                                                        int* __restrict__ idxbuf,
                                                        int* __restrict__ tcnt,
                                                        int n, int ncap) {
  int i = blockIdx.x * 256 + threadIdx.x;
  int lane = threadIdx.x & 63;
  int t = (i < n) ? ntype[i] : -1;
  unsigned long long m0 = __ballot(t == 0);
  unsigned long long m1 = __ballot(t == 1);
  int b0 = 0, b1 = 0;
  if (lane == 0) {
    b0 = atomicAdd(&tcnt[0], (int)__popcll(m0));
    b1 = atomicAdd(&tcnt[1], (int)__popcll(m1));
  }
  b0 = __shfl(b0, 0);
  b1 = __shfl(b1, 0);
  unsigned long long below = (1ull << lane) - 1ull;
  if (t == 0) idxbuf[b0 + (int)__popcll(m0 & below)] = i;
  else if (t == 1) idxbuf[ncap + b1 + (int)__popcll(m1 & below)] = i;
}

// ---------------- W fragment prep (once): hi/lo bf16 frags, frag-major ----------------

template <int IN>
__global__ __launch_bounds__(256) void prep_w(const float* __restrict__ eW,
                                              float* __restrict__ wfh,
                                              float* __restrict__ wfl) {
  constexpr int KC = IN / 32;
  int id = blockIdx.x * 256 + threadIdx.x;
  if (id >= 12 * KC * 64) return;
  int lane = id & 63;
  int fk = id >> 6;
  int kc = fk % KC, ct = fk / KC;
  int n = ct * 16 + (lane & 15);
  int kb = kc * 32 + ((lane >> 4) & 3) * 8;
  int half = (n >= 96) ? 1 : 0;
  int jj = n - 96 * half;
  int e = jj >> 5, o = jj & 31;
  const float* wp = eW + ((size_t)((e * 2 + half) * IN) + kb) * 32 + o;
  bf16x8_t hv, lv;
#pragma unroll
  for (int j = 0; j < 8; ++j) {
    unsigned short h, l;
    cvt_split(wp[(size_t)j * 32], h, l);
    hv[j] = (short)h;
    lv[j] = (short)l;
  }
  *(bf16x8_t*)(wfh + (size_t)id * 4) = hv;
  *(bf16x8_t*)(wfl + (size_t)id * 4) = lv;
}

// ---------------- node projection GEMM via MFMA ----------------

template <int IN>
__global__ __launch_bounds__(256) void proj_mfma(const float* __restrict__ X,
                                                 const float* __restrict__ wfh,
                                                 const float* __restrict__ wfl,
                                                 float* __restrict__ P, int n) {
  constexpr int KC = IN / 32;
  __shared__ short Ah[4 * KC * 64 * 8];
  __shared__ short Al[4 * KC * 64 * 8];
  const int tx = threadIdx.x;
  const int base = blockIdx.x * 64;

  for (int q = tx; q < 4 * KC * 64; q += 256) {
    int lane = q & 63;
    int fk = q >> 6;
    int kc = fk % KC, nt = fk / KC;
    int node = base + nt * 16 + (lane & 15);
    int kb = kc * 32 + ((lane >> 4) & 3) * 8;
    float xs[8];
    if (node < n) {
      float4 a = *(const float4*)(X + (size_t)node * IN + kb);
      float4 b = *(const float4*)(X + (size_t)node * IN + kb + 4);
      xs[0] = a.x; xs[1] = a.y; xs[2] = a.z; xs[3] = a.w;
      xs[4] = b.x; xs[5] = b.y; xs[6] = b.z; xs[7] = b.w;
    } else {
#pragma unroll
      for (int j = 0; j < 8; ++j) xs[j] = 0.f;
    }
    bf16x8_t hv, lv;
#pragma unroll
    for (int j = 0; j < 8; ++j) {
      unsigned short h, l;
      cvt_split(xs[j], h, l);
      hv[j] = (short)h;
      lv[j] = (short)l;
    }
    *(bf16x8_t*)(Ah + (size_t)q * 8) = hv;
    *(bf16x8_t*)(Al + (size_t)q * 8) = lv;
  }
  __syncthreads();

  const int wave = tx >> 6;
  const int lane = tx & 63;

  f32x4_t acc[4][3];
#pragma unroll
  for (int nt = 0; nt < 4; ++nt)
#pragma unroll
    for (int c = 0; c < 3; ++c) acc[nt][c] = (f32x4_t){0.f, 0.f, 0.f, 0.f};

  for (int kc = 0; kc < KC; ++kc) {
    bf16x8_t Bh[3], Bl[3];
#pragma unroll
    for (int c = 0; c < 3; ++c) {
      int ct = wave * 3 + c;
      size_t idx = ((size_t)(ct * KC + kc) * 64 + lane) * 4;
      Bh[c] = *(const bf16x8_t*)(wfh + idx);
      Bl[c] = *(const bf16x8_t*)(wfl + idx);
    }
#pragma unroll
    for (int nt = 0; nt < 4; ++nt) {
      size_t idx = ((size_t)(nt * KC + kc) * 64 + lane) * 8;
      bf16x8_t ah = *(const bf16x8_t*)(Ah + idx);
      bf16x8_t al = *(const bf16x8_t*)(Al + idx);
#pragma unroll
      for (int c = 0; c < 3; ++c) {
        acc[nt][c] = __builtin_amdgcn_mfma_f32_16x16x32_bf16(ah, Bh[c], acc[nt][c], 0, 0, 0);
        acc[nt][c] = __builtin_amdgcn_mfma_f32_16x16x32_bf16(ah, Bl[c], acc[nt][c], 0, 0, 0);
        acc[nt][c] = __builtin_amdgcn_mfma_f32_16x16x32_bf16(al, Bh[c], acc[nt][c], 0, 0, 0);
      }
    }
  }

  const int row0 = ((lane >> 4) & 3) * 4;
  const int col = lane & 15;
#pragma unroll
  for (int nt = 0; nt < 4; ++nt) {
#pragma unroll
    for (int c = 0; c < 3; ++c) {
      int jcol = (wave * 3 + c) * 16 + col;
#pragma unroll
      for (int r = 0; r < 4; ++r) {
        int node = base + nt * 16 + row0 + r;
        if (node < n) P[(size_t)node * 192 + jcol] = acc[nt][c][r];
      }
    }
  }
}

// ---------------- edge aggregation (unroll-4 MLP; et in edata low bits) ----------------

#define ACC_EDGE(pk, v)                                      \
  {                                                          \
    int et_ = (pk) & 3;                                      \
    float pb_ = (et_ == 0) ? pdb0 : ((et_ == 1) ? pdb1 : pdb2); \
    float m_ = fmaxf((v) + pb_, 0.f);                        \
    a0 += (et_ == 0) ? m_ : 0.f;                             \
    a1 += (et_ == 1) ? m_ : 0.f;                             \
    a2 += (et_ == 2) ? m_ : 0.f;                             \
    c0 += (et_ == 0);                                        \
    c1 += (et_ == 1);                                        \
  }

__global__ __launch_bounds__(256) void aggregate_kernel(const float* __restrict__ P,
                                                        const int* __restrict__ rowstart,
                                                        const int* __restrict__ edata,
                                                        const float* __restrict__ eb,
                                                        float* __restrict__ h, int n) {
  int wid = (blockIdx.x * 256 + threadIdx.x) >> 6;
  if (wid >= n) return;
  int lane = threadIdx.x & 63;
  int o = lane & 31, slot = lane >> 5;
  const float* Pd = P + (size_t)wid * 192 + 96;
  float pdb0 = Pd[o] + eb[o];
  float pdb1 = Pd[32 + o] + eb[32 + o];
  float pdb2 = Pd[64 + o] + eb[64 + o];
  int s = rowstart[wid], e = rowstart[wid + 1];
  const char* Pb = (const char*)P;
  int o4 = o * 4;
  float a0 = 0.f, a1 = 0.f, a2 = 0.f;
  int c0 = 0, c1 = 0;
  int i = s + slot;
  // main: 4 edges per slot-iteration -> 8 independent P loads in flight per wave
  for (; i + 6 < e; i += 8) {
    int p0 = edata[i];
    int p1 = edata[i + 2];
    int p2 = edata[i + 4];
    int p3 = edata[i + 6];
    float v0 = *(const float*)(Pb + (p0 & ~3) + o4);
    float v1 = *(const float*)(Pb + (p1 & ~3) + o4);
    float v2 = *(const float*)(Pb + (p2 & ~3) + o4);
    float v3 = *(const float*)(Pb + (p3 & ~3) + o4);
    ACC_EDGE(p0, v0)
    ACC_EDGE(p1, v1)
    ACC_EDGE(p2, v2)
    ACC_EDGE(p3, v3)
  }
  for (; i < e; i += 2) {
    int pk = edata[i];
    float v = *(const float*)(Pb + (pk & ~3) + o4);
    ACC_EDGE(pk, v)
  }
  a0 += __shfl_xor(a0, 32);
  a1 += __shfl_xor(a1, 32);
  a2 += __shfl_xor(a2, 32);
  c0 += __shfl_xor(c0, 32);
  c1 += __shfl_xor(c1, 32);
  if (slot == 0) {
    int total = e - s;
    float* hn = h + (size_t)wid * 96;
    hn[o] = a0 / fmaxf((float)c0, 1.f);
    hn[32 + o] = a1 / fmaxf((float)c1, 1.f);
    hn[64 + o] = a2 / fmaxf((float)(total - c0 - c1), 1.f);
  }
}

// ---------------- node MLP (type-partitioned), quad-transposed Ws ----------------

template <int OUT>
__global__ __launch_bounds__(256) void mlp2_kernel(const float* __restrict__ H,
                                                   const float* __restrict__ nW,
                                                   const float* __restrict__ nb,
                                                   const int* __restrict__ idxbuf,
                                                   const int* __restrict__ tcnt,
                                                   float* __restrict__ out, int ncap) {
  constexpr int CO = OUT / 32;
  __shared__ float Xs[64 * 32];
  __shared__ float Ws[8 * OUT * 4];

  int c0 = tcnt[0];
  int nb0 = (c0 + 63) >> 6;
  int t, base, cnt;
  if ((int)blockIdx.x < nb0) {
    t = 0; base = blockIdx.x << 6; cnt = c0;
  } else {
    t = 1; base = ((int)blockIdx.x - nb0) << 6; cnt = tcnt[1];
    if (base >= cnt) return;
  }
  const float* W = nW + (size_t)t * 96 * OUT;
  const float* bias = nb + t * OUT;
  const int* il = idxbuf + (size_t)t * ncap;

  const int tx = threadIdx.x;
  const int t32 = tx & 31;
  const int ng = tx >> 5;

  float acc[8][CO];
#pragma unroll
  for (int i = 0; i < 8; ++i)
#pragma unroll
    for (int c = 0; c < CO; ++c) acc[i][c] = 0.f;

  for (int k0 = 0; k0 < 96; k0 += 32) {
    for (int id = tx; id < 512; id += 256) {
      int i = id >> 3, kk4 = (id & 7) * 4;
      float4 v = make_float4(0.f, 0.f, 0.f, 0.f);
      if (base + i < cnt) {
        int row = il[base + i];
        v = *(const float4*)(H + (size_t)row * 96 + k0 + kk4);
      }
      *(float4*)(Xs + i * 32 + kk4) = v;
    }
    for (int id = tx; id < 8 * OUT; id += 256) {
      int g = id / OUT;
      int j = id % OUT;
      const float* wp = W + (size_t)(k0 + 4 * g) * OUT + j;
      float4 v = make_float4(wp[0], wp[OUT], wp[2 * OUT], wp[3 * OUT]);
      *(float4*)(Ws + (size_t)id * 4) = v;
    }
    __syncthreads();
#pragma unroll
    for (int g = 0; g < 8; ++g) {
      float4 xv[8], wv[CO];
#pragma unroll
      for (int i = 0; i < 8; ++i) xv[i] = *(const float4*)(Xs + (ng * 8 + i) * 32 + 4 * g);
#pragma unroll
      for (int c = 0; c < CO; ++c) wv[c] = *(const float4*)(Ws + ((size_t)g * OUT + t32 + 32 * c) * 4);
#pragma unroll
      for (int i = 0; i < 8; ++i)
#pragma unroll
        for (int c = 0; c < CO; ++c) {
          acc[i][c] = fmaf(xv[i].x, wv[c].x, acc[i][c]);
          acc[i][c] = fmaf(xv[i].y, wv[c].y, acc[i][c]);
          acc[i][c] = fmaf(xv[i].z, wv[c].z, acc[i][c]);
          acc[i][c] = fmaf(xv[i].w, wv[c].w, acc[i][c]);
        }
    }
    __syncthreads();
  }

  float bj[CO];
#pragma unroll
  for (int c = 0; c < CO; ++c) bj[c] = bias[t32 + 32 * c];
#pragma unroll
  for (int i = 0; i < 8; ++i) {
    int slot = base + ng * 8 + i;
    if (slot < cnt) {
      int row = il[slot];
#pragma unroll
      for (int c = 0; c < CO; ++c)
        out[(size_t)row * OUT + t32 + 32 * c] = fmaxf(acc[i][c] + bj[c], 0.f);
    }
  }
}

// ---------------- launch ----------------

extern "C" void kernel_launch(void* const* d_in, const int* in_sizes, int n_in,
                              void* d_out, int out_size, void* d_ws, size_t ws_size,
                              hipStream_t stream) {
  const float* nf    = (const float*)d_in[0];
  const int*   eidx  = (const int*)d_in[1];
  const int*   etype = (const int*)d_in[2];
  const int*   ntype = (const int*)d_in[3];
  const float* eW0   = (const float*)d_in[4];
  const float* eb0   = (const float*)d_in[5];
  const float* nW0   = (const float*)d_in[6];
  const float* nb0   = (const float*)d_in[7];
  const float* eW1   = (const float*)d_in[8];
  const float* eb1   = (const float*)d_in[9];
  const float* nW1   = (const float*)d_in[10];
  const float* nb1   = (const float*)d_in[11];
  const int N = in_sizes[3];
  const int E = in_sizes[2];
  const int* srcv = eidx;
  const int* dstv = eidx + E;

  // workspace layout; rank aliases h96, deg8 aliases h64 (CSR build completes
  // before aggregate/mlp write those buffers — stream-ordered).
  float* P   = (float*)d_ws;                     // N*192
  float* h96 = P + (size_t)N * 192;              // N*96
  float* h64 = h96 + (size_t)N * 96;             // N*64
  int* rowstart = (int*)(h64 + (size_t)N * 64);  // N+1 (padded)
  int* tcnt     = rowstart + ((N + 4) & ~3);     // 2
  int* bsum     = tcnt + 2;                      // 64
  int* boff     = bsum + 64;                     // 64
  int* idxbuf   = boff + 64;                     // 2*N
  int* edata    = idxbuf + 2 * N;                // E
  float* wf0h   = (float*)(edata + E);           // 12288
  float* wf0l   = wf0h + 12288;                  // 12288
  float* wf1h   = wf0l + 12288;                  // 6144
  float* wf1l   = wf1h + 6144;                   // 6144
  int* rank     = (int*)h96;                     // E  (alias)
  int* deg8     = (int*)h64;                     // 8N (alias)

  const int nsb = (N + 1023) / 1024;
  const int egrid = (E + 255) / 256;

  hipMemsetAsync(deg8, 0, (size_t)N * 8 * sizeof(int), stream);
  hipMemsetAsync(tcnt, 0, 2 * sizeof(int), stream);
  prep_w<128><<<12, 256, 0, stream>>>(eW0, wf0h, wf0l);
  prep_w<64><<<6, 256, 0, stream>>>(eW1, wf1h, wf1l);
  rank_kernel<<<egrid, 256, 0, stream>>>(dstv, deg8, rank, E);
  scan1_kernel<<<nsb, 256, 0, stream>>>(deg8, rowstart, bsum, N);
  scan2_kernel<<<1, 64, 0, stream>>>(bsum, boff, nsb, rowstart, N);
  scan3_kernel<<<(N + 255) / 256, 256, 0, stream>>>(rowstart, boff, N);
  fill_kernel<<<egrid, 256, 0, stream>>>(srcv, dstv, etype, rank, rowstart, deg8, edata, E);
  partition_kernel<<<(N + 255) / 256, 256, 0, stream>>>(ntype, idxbuf, tcnt, N, N);

  const int pgrid = (N + 63) / 64;
  int agrid = (N + 3) / 4;
  int mgrid = (N + 63) / 64 + 2;

  // layer 0: 128 -> 64
  proj_mfma<128><<<pgrid, 256, 0, stream>>>(nf, wf0h, wf0l, P, N);
  aggregate_kernel<<<agrid, 256, 0, stream>>>(P, rowstart, edata, eb0, h96, N);
  mlp2_kernel<64><<<mgrid, 256, 0, stream>>>(h96, nW0, nb0, idxbuf, tcnt, h64, N);

  // layer 1: 64 -> 128
  proj_mfma<64><<<pgrid, 256, 0, stream>>>(h64, wf1h, wf1l, P, N);
  aggregate_kernel<<<agrid, 256, 0, stream>>>(P, rowstart, edata, eb1, h96, N);
  mlp2_kernel<128><<<mgrid, 256, 0, stream>>>(h96, nW1, nb1, idxbuf, tcnt, (float*)d_out, N);
}